// Round 8
// baseline (9181.542 us; speedup 1.0000x reference)
//
#include <hip/hip_runtime.h>

static constexpr int INN  = 4096;
static constexpr int HID  = 8192;
static constexpr int OUTN = 2048;
static constexpr float LR  = 0.01f;
static constexpr float B1  = 0.9f;
static constexpr float B2  = 0.999f;
static constexpr float EPS = 1e-8f;

static constexpr int NB = 512;               // main-kernel blocks
static constexpr int NT = 512;               // threads per block (8 waves)
static constexpr int RPB = HID / NB;         // 16 rows per block (2 per wave)
static constexpr int CPB = OUTN / NB;        // 4 cols per block

// ---- workspace layout (float offsets) ----
static constexpr int PH    = 0;              // [8192]      b_h + rho(x)@W1
static constexpr int HS    = PH + HID;       // [3][8192]   h, mh, vh
static constexpr int OS    = HS + 3 * HID;   // [3][2048]   o, mo, vo
static constexpr int RHOO  = OS + 3 * OUTN;  // [2048]      rho(o)
static constexpr int BAR   = RHOO + OUTN;    // [512]       barrier (uints)
static constexpr int WPART = BAR + 512;      // [512][2048] w block-partials
static constexpr int ZBASE = HS;
static constexpr int ZLEN  = WPART - HS;     // 33280 floats (incl. BAR)

__device__ __forceinline__ float rho01(float v) { return fminf(fmaxf(v, 0.f), 1.f); }

// ---------------- setup: ph = b_h + rho(x)@W1 ; zero state + barrier ----------------
__global__ void __launch_bounds__(256)
k_setup(const float* __restrict__ x, const float* __restrict__ W1,
        const float* __restrict__ b_h, float* __restrict__ ws)
{
    const int t = threadIdx.x, b = blockIdx.x;
    if (b < 256) {
        __shared__ float rx[INN];
        __shared__ float red[256];
        #pragma unroll
        for (int k = 0; k < INN / 256; ++k) rx[k * 256 + t] = rho01(x[k * 256 + t]);
        __syncthreads();
        const int j  = b * 32 + (t & 31);
        const int r0 = t >> 5;
        float acc = 0.f;
        #pragma unroll 8
        for (int k = 0; k < 512; ++k) {
            const int i = r0 + 8 * k;
            acc = fmaf(rx[i], W1[(size_t)i * HID + j], acc);
        }
        red[t] = acc;
        __syncthreads();
        if (t < 32) {
            float s = 0.f;
            #pragma unroll
            for (int q = 0; q < 8; ++q) s += red[q * 32 + t];
            const int jj = b * 32 + t;
            ws[PH + jj] = s + b_h[jj];
        }
    } else {
        const int zb = b - 256;   // 0..7
        #pragma unroll
        for (int k = 0; k < 17; ++k) {
            const int idx = k * 2048 + zb * 256 + t;
            if (idx < ZLEN) ws[ZBASE + idx] = 0.f;
        }
    }
}

// ---------------- cheap grid barrier: sharded monotonic counters + release flag ----
// counters at bar[i*16] (i<16, 64B apart); release at bar[496].
__device__ __forceinline__ void grid_bar(unsigned* bar, int blk, int tid, unsigned e)
{
    __syncthreads();
    if (tid == 0) {
        __threadfence();
        __hip_atomic_fetch_add(&bar[(blk & 15) * 16], 1u,
                               __ATOMIC_RELEASE, __HIP_MEMORY_SCOPE_AGENT);
        if (blk == 0) {
            const unsigned target = (unsigned)NB * e;
            for (;;) {
                unsigned s = 0;
                #pragma unroll
                for (int i = 0; i < 16; ++i)
                    s += __hip_atomic_load(&bar[i * 16],
                                           __ATOMIC_ACQUIRE, __HIP_MEMORY_SCOPE_AGENT);
                if (s >= target) break;
                __builtin_amdgcn_s_sleep(2);
            }
            __hip_atomic_store(&bar[496], e,
                               __ATOMIC_RELEASE, __HIP_MEMORY_SCOPE_AGENT);
        } else {
            while (__hip_atomic_load(&bar[496],
                                     __ATOMIC_ACQUIRE, __HIP_MEMORY_SCOPE_AGENT) < e)
                __builtin_amdgcn_s_sleep(2);
        }
        __threadfence();
    }
    __syncthreads();
}

// ---------------- main: all T iterations, 2 grid barriers each ----------------
// Block b: rows [16b,16b+16) (2/wave), cols [4b,4b+4) (1 per wave, waves 0-3).
__global__ void __launch_bounds__(NT, 4)
k_main(const float* __restrict__ W2, const float* __restrict__ b_o,
       float* __restrict__ ws, float* __restrict__ out, const int* __restrict__ nit)
{
    __shared__ float wsum[OUTN];     // 8 KB: block col-partials
    __shared__ float rol[OUTN];      // 8 KB: staged rho(o)

    const int tid = threadIdx.x, blk = blockIdx.x;
    const int lane = tid & 63, wv = tid >> 6;
    unsigned* bar = reinterpret_cast<unsigned*>(ws + BAR);
    float* hv = ws + HS;
    float* hm = ws + HS + HID;
    float* hq = ws + HS + 2 * HID;
    float* ov = ws + OS;
    float* om = ws + OS + OUTN;
    float* oq = ws + OS + 2 * OUTN;
    float* rhoO = ws + RHOO;
    float* wp   = ws + WPART;
    const float* ph = ws + PH;

    const int T  = nit[0];
    const int i0 = blk * RPB + wv * 2;     // 2 rows per wave
    const int j0 = blk * CPB;

    float b1t = 1.f, b2t = 1.f;
    unsigned e = 0;

    for (int t = 1; t <= T; ++t) {
        b1t *= B1; b2t *= B2;
        const float ub1 = 1.f / (1.f - b1t);
        const float ub2 = 1.f / (1.f - b2t);

        // stage rho(o) into LDS (coalesced float4), zero wsum
        reinterpret_cast<float4*>(rol)[tid] =
            reinterpret_cast<const float4*>(rhoO)[tid];
        reinterpret_cast<float4*>(wsum)[tid] = make_float4(0.f, 0.f, 0.f, 0.f);
        __syncthreads();

        // per-lane rho(o) slice: cols lane+64k
        float ro[32];
        #pragma unroll
        for (int k = 0; k < 32; ++k) ro[k] = rol[lane + 64 * k];

        float wacc[32];
        #pragma unroll
        for (int k = 0; k < 32; ++k) wacc[k] = 0.f;

        float u0, u1, h0, h1;
        {
            const float* row = W2 + (size_t)i0 * OUTN;
            h0 = hv[i0];
            const float rh = rho01(h0);
            float acc = 0.f;
            #pragma unroll
            for (int k = 0; k < 32; ++k) {
                const float w = row[lane + 64 * k];
                acc = fmaf(w, ro[k], acc);
                wacc[k] = fmaf(rh, w, wacc[k]);
            }
            #pragma unroll
            for (int off = 1; off < 64; off <<= 1) acc += __shfl_xor(acc, off, 64);
            u0 = acc;
        }
        {
            const float* row = W2 + (size_t)(i0 + 1) * OUTN;
            h1 = hv[i0 + 1];
            const float rh = rho01(h1);
            float acc = 0.f;
            #pragma unroll
            for (int k = 0; k < 32; ++k) {
                const float w = row[lane + 64 * k];
                acc = fmaf(w, ro[k], acc);
                wacc[k] = fmaf(rh, w, wacc[k]);
            }
            #pragma unroll
            for (int off = 1; off < 64; off <<= 1) acc += __shfl_xor(acc, off, 64);
            u1 = acc;
        }

        // h-Adam: lanes 0,1 handle rows i0, i0+1 (static selects, no indexed array)
        if (lane < 2) {
            const int i   = i0 + lane;
            const float h = (lane == 0) ? h0 : h1;
            const float u = (lane == 0) ? u0 : u1;
            float m = hm[i], v = hq[i];
            const float mask = (h >= 0.f && h <= 1.f) ? 1.f : 0.f;
            const float g = h - mask * (ph[i] + u);
            m = B1 * m + (1.f - B1) * g;
            v = B2 * v + (1.f - B2) * g * g;
            hv[i] = h - LR * (m * ub1) / (sqrtf(v * ub2) + EPS);
            hm[i] = m; hq[i] = v;
        }

        // accumulate col-partials (2 lanes/bank -> conflict-free)
        #pragma unroll
        for (int k = 0; k < 32; ++k) atomicAdd(&wsum[lane + 64 * k], wacc[k]);
        __syncthreads();

        // write block partials, coalesced float4
        reinterpret_cast<float4*>(wp + (size_t)blk * OUTN)[tid] =
            reinterpret_cast<const float4*>(wsum)[tid];

        grid_bar(bar, blk, tid, ++e);

        // o-phase: waves 0..3, one column each
        if (wv < CPB) {
            const int j = j0 + wv;
            float s = 0.f;
            #pragma unroll
            for (int k = 0; k < 8; ++k)
                s += wp[(size_t)(lane + 64 * k) * OUTN + j];
            #pragma unroll
            for (int off = 1; off < 64; off <<= 1) s += __shfl_xor(s, off, 64);
            if (lane == 0) {
                float o = ov[j], m = om[j], v = oq[j];
                const float mask = (o >= 0.f && o <= 1.f) ? 1.f : 0.f;
                const float g = o - mask * (b_o[j] + s);
                m = B1 * m + (1.f - B1) * g;
                v = B2 * v + (1.f - B2) * g * g;
                o = o - LR * (m * ub1) / (sqrtf(v * ub2) + EPS);
                ov[j] = o; om[j] = m; oq[j] = v;
                rhoO[j] = rho01(o);
                out[j]  = o;
            }
        }

        grid_bar(bar, blk, tid, ++e);
    }
}

extern "C" void kernel_launch(void* const* d_in, const int* in_sizes, int n_in,
                              void* d_out, int out_size, void* d_ws, size_t ws_size,
                              hipStream_t stream) {
    const float* x  = (const float*)d_in[0];
    const float* W1 = (const float*)d_in[1];
    const float* W2 = (const float*)d_in[2];
    const float* bh = (const float*)d_in[3];
    const float* bo = (const float*)d_in[4];
    const int*  nit = (const int*)d_in[5];
    float* out = (float*)d_out;
    float* ws  = (float*)d_ws;

    k_setup<<<264, 256, 0, stream>>>(x, W1, bh, ws);
    k_main<<<NB, NT, 0, stream>>>(W2, bo, ws, out, nit);
}

// Round 10
// 2081.158 us; speedup vs baseline: 4.4117x; 4.4117x over previous
//
#include <hip/hip_runtime.h>

static constexpr int INN  = 4096;
static constexpr int HID  = 8192;
static constexpr int OUTN = 2048;
static constexpr float LR  = 0.01f;
static constexpr float B1  = 0.9f;
static constexpr float B2  = 0.999f;
static constexpr float EPS = 1e-8f;

static constexpr int NB = 512;     // k_iter blocks
static constexpr int NT = 512;     // threads (8 waves)
static constexpr int RPB = HID / NB;          // 16 rows/block (2 per wave)
static constexpr int NSH = 4;                 // w-slot shards

// ---- workspace layout (float offsets) ----
static constexpr int PH  = 0;                 // [8192] b_h + rho(x)@W1
static constexpr int HV  = PH + HID;          // [8192] h
static constexpr int HM  = HV + HID;          // [8192] m_h
static constexpr int HQ  = HM + HID;          // [8192] v_h
static constexpr int OST = HQ + HID;          // [2][3][2048] o-state (parity)
static constexpr int WSL = OST + 2 * 3 * OUTN;// [31][4][2048] w slots, sharded
static constexpr int END = WSL + 31 * NSH * OUTN;
static constexpr int ZBASE = HV;
static constexpr int ZLEN  = END - HV;        // 290816 floats

__device__ __forceinline__ float rho01(float v) { return fminf(fmaxf(v, 0.f), 1.f); }

__device__ __forceinline__ float adam1(float p, float& m, float& v, float g,
                                       float ub1, float ub2)
{
    m = B1 * m + (1.f - B1) * g;
    v = B2 * v + (1.f - B2) * g * g;
    return p - LR * (m * ub1) / (sqrtf(v * ub2) + EPS);
}

// ---------------- setup: ph = b_h + rho(x)@W1 ; zero all state ----------------
__global__ void __launch_bounds__(256)
k_setup(const float* __restrict__ x, const float* __restrict__ W1,
        const float* __restrict__ b_h, float* __restrict__ ws)
{
    const int t = threadIdx.x, b = blockIdx.x;
    if (b < 256) {
        __shared__ float rx[INN];
        __shared__ float red[256];
        #pragma unroll
        for (int k = 0; k < INN / 256; ++k) rx[k * 256 + t] = rho01(x[k * 256 + t]);
        __syncthreads();
        const int j  = b * 32 + (t & 31);
        const int r0 = t >> 5;
        float acc = 0.f;
        #pragma unroll 8
        for (int k = 0; k < 512; ++k) {
            const int i = r0 + 8 * k;
            acc = fmaf(rx[i], W1[(size_t)i * HID + j], acc);
        }
        red[t] = acc;
        __syncthreads();
        if (t < 32) {
            float s = 0.f;
            #pragma unroll
            for (int q = 0; q < 8; ++q) s += red[q * 32 + t];
            const int jj = b * 32 + t;
            ws[PH + jj] = s + b_h[jj];
        }
    } else {
        const int zb = b - 256;               // 0..15
        #pragma unroll
        for (int k = 0; k < 71; ++k)          // 71*4096 == ZLEN exactly
            ws[ZBASE + k * 4096 + zb * 256 + t] = 0.f;
    }
}

// ---------------- k_iter: phase O (o_{t-1}) + phase U (h_t, w_slot[t]) ----------------
__global__ void __launch_bounds__(NT, 4)
k_iter(const float* __restrict__ W2, const float* __restrict__ b_o,
       float* __restrict__ ws, const int* __restrict__ nit, int t,
       float ubo1, float ubo2, float ubh1, float ubh2)
{
    if (nit[0] < t) return;
    __shared__ float rol[OUTN];      // rho(o_{t-1})
    __shared__ float wsum[OUTN];     // block col-partials
    const int tid = threadIdx.x, blk = blockIdx.x;
    const int lane = tid & 63, wv = tid >> 6;
    const int j0 = tid * 4;

    // ---- phase O: compute o_{t-1} redundantly; owner block writes state ----
    if (t == 1) {
        reinterpret_cast<float4*>(rol)[tid] = make_float4(0.f, 0.f, 0.f, 0.f);
    } else {
        const int pin  = t & 1;              // parity of o_{t-2}
        const int pout = (t - 1) & 1;        // parity of o_{t-1}
        const float* oso = ws + OST + pin * 3 * OUTN;
        const float* osm = oso + OUTN;
        const float* osv = osm + OUTN;
        float* nso = ws + OST + pout * 3 * OUTN;
        float* nsm = nso + OUTN;
        float* nsv = nsm + OUTN;
        const float* wsl = ws + WSL + (size_t)(t - 1) * NSH * OUTN;

        float4 o4 = *reinterpret_cast<const float4*>(oso + j0);
        float4 m4 = *reinterpret_cast<const float4*>(osm + j0);
        float4 v4 = *reinterpret_cast<const float4*>(osv + j0);
        float4 b4 = *reinterpret_cast<const float4*>(b_o + j0);
        float4 w4 = *reinterpret_cast<const float4*>(wsl + j0);
        #pragma unroll
        for (int s = 1; s < NSH; ++s) {
            const float4 a = *reinterpret_cast<const float4*>(wsl + s * OUTN + j0);
            w4.x += a.x; w4.y += a.y; w4.z += a.z; w4.w += a.w;
        }
        #define GOO(c) ((o4.c >= 0.f && o4.c <= 1.f) ? (o4.c - (b4.c + w4.c)) : o4.c)
        const float gx = GOO(x), gy = GOO(y), gz = GOO(z), gw = GOO(w);
        #undef GOO
        o4.x = adam1(o4.x, m4.x, v4.x, gx, ubo1, ubo2);
        o4.y = adam1(o4.y, m4.y, v4.y, gy, ubo1, ubo2);
        o4.z = adam1(o4.z, m4.z, v4.z, gz, ubo1, ubo2);
        o4.w = adam1(o4.w, m4.w, v4.w, gw, ubo1, ubo2);
        reinterpret_cast<float4*>(rol)[tid] =
            make_float4(rho01(o4.x), rho01(o4.y), rho01(o4.z), rho01(o4.w));
        if (tid == blk) {                    // owner writes cols [4blk,4blk+4)
            *reinterpret_cast<float4*>(nso + j0) = o4;
            *reinterpret_cast<float4*>(nsm + j0) = m4;
            *reinterpret_cast<float4*>(nsv + j0) = v4;
        }
    }
    reinterpret_cast<float4*>(wsum)[tid] = make_float4(0.f, 0.f, 0.f, 0.f);
    __syncthreads();

    // ---- phase U: 2 rows/wave fused pass over W2 ----
    const int i0 = blk * RPB + wv * 2;
    float* hv = ws + HV;
    float* hm = ws + HM;
    float* hq = ws + HQ;
    const float* ph = ws + PH;

    const float4* rol4 = reinterpret_cast<const float4*>(rol);
    float4 rv[8];
    #pragma unroll
    for (int k = 0; k < 8; ++k) rv[k] = rol4[lane + 64 * k];

    float4 wacc[8];
    #pragma unroll
    for (int k = 0; k < 8; ++k) wacc[k] = make_float4(0.f, 0.f, 0.f, 0.f);

    float u0, u1, h0, h1;
    {
        const float4* row4 = reinterpret_cast<const float4*>(W2 + (size_t)i0 * OUTN);
        h0 = hv[i0];
        const float rh = rho01(h0);
        float4 s4 = make_float4(0.f, 0.f, 0.f, 0.f);
        #pragma unroll
        for (int k = 0; k < 8; ++k) {
            const float4 a = row4[lane + 64 * k];
            s4.x = fmaf(a.x, rv[k].x, s4.x);
            s4.y = fmaf(a.y, rv[k].y, s4.y);
            s4.z = fmaf(a.z, rv[k].z, s4.z);
            s4.w = fmaf(a.w, rv[k].w, s4.w);
            wacc[k].x = fmaf(rh, a.x, wacc[k].x);
            wacc[k].y = fmaf(rh, a.y, wacc[k].y);
            wacc[k].z = fmaf(rh, a.z, wacc[k].z);
            wacc[k].w = fmaf(rh, a.w, wacc[k].w);
        }
        u0 = (s4.x + s4.y) + (s4.z + s4.w);
    }
    {
        const float4* row4 = reinterpret_cast<const float4*>(W2 + (size_t)(i0 + 1) * OUTN);
        h1 = hv[i0 + 1];
        const float rh = rho01(h1);
        float4 s4 = make_float4(0.f, 0.f, 0.f, 0.f);
        #pragma unroll
        for (int k = 0; k < 8; ++k) {
            const float4 a = row4[lane + 64 * k];
            s4.x = fmaf(a.x, rv[k].x, s4.x);
            s4.y = fmaf(a.y, rv[k].y, s4.y);
            s4.z = fmaf(a.z, rv[k].z, s4.z);
            s4.w = fmaf(a.w, rv[k].w, s4.w);
            wacc[k].x = fmaf(rh, a.x, wacc[k].x);
            wacc[k].y = fmaf(rh, a.y, wacc[k].y);
            wacc[k].z = fmaf(rh, a.z, wacc[k].z);
            wacc[k].w = fmaf(rh, a.w, wacc[k].w);
        }
        u1 = (s4.x + s4.y) + (s4.z + s4.w);
    }
    #pragma unroll
    for (int off = 1; off < 64; off <<= 1) u0 += __shfl_xor(u0, off, 64);
    #pragma unroll
    for (int off = 1; off < 64; off <<= 1) u1 += __shfl_xor(u1, off, 64);

    // h-Adam: lanes 0,1 own rows i0, i0+1
    if (lane < 2) {
        const int i   = i0 + lane;
        const float h = (lane == 0) ? h0 : h1;
        const float u = (lane == 0) ? u0 : u1;
        float m = hm[i], v = hq[i];
        const float mask = (h >= 0.f && h <= 1.f) ? 1.f : 0.f;
        const float g = h - mask * (ph[i] + u);
        hv[i] = adam1(h, m, v, g, ubh1, ubh2);
        hm[i] = m; hq[i] = v;
    }

    // LDS reduce col-partials
    #pragma unroll
    for (int k = 0; k < 8; ++k) {
        const int c = 4 * (lane + 64 * k);
        atomicAdd(&wsum[c + 0], wacc[k].x);
        atomicAdd(&wsum[c + 1], wacc[k].y);
        atomicAdd(&wsum[c + 2], wacc[k].z);
        atomicAdd(&wsum[c + 3], wacc[k].w);
    }
    __syncthreads();

    // sharded global accumulate into w_slot[t]
    float* wnew = ws + WSL + ((size_t)t * NSH + (blk & (NSH - 1))) * OUTN;
    atomicAdd(&wnew[j0 + 0], wsum[j0 + 0]);
    atomicAdd(&wnew[j0 + 1], wsum[j0 + 1]);
    atomicAdd(&wnew[j0 + 2], wsum[j0 + 2]);
    atomicAdd(&wnew[j0 + 3], wsum[j0 + 3]);
}

// ---------------- k_fin: final o_T -> out ----------------
__global__ void __launch_bounds__(512)
k_fin(const float* __restrict__ b_o, float* __restrict__ ws,
      float* __restrict__ out, const int* __restrict__ nit)
{
    const int T = nit[0];
    const float p1 = powf(B1, (float)T), p2 = powf(B2, (float)T);
    const float ub1 = 1.f / (1.f - p1), ub2 = 1.f / (1.f - p2);
    const int j = blockIdx.x * 512 + threadIdx.x;
    const int pin = (T - 1) & 1;             // parity of o_{T-1}
    const float* oso = ws + OST + pin * 3 * OUTN;
    float o = oso[j], m = oso[OUTN + j], v = oso[2 * OUTN + j];
    const float* wsl = ws + WSL + (size_t)T * NSH * OUTN;
    float w = 0.f;
    #pragma unroll
    for (int s = 0; s < NSH; ++s) w += wsl[s * OUTN + j];
    const float mask = (o >= 0.f && o <= 1.f) ? 1.f : 0.f;
    const float g = o - mask * (b_o[j] + w);
    out[j] = adam1(o, m, v, g, ub1, ub2);
}

extern "C" void kernel_launch(void* const* d_in, const int* in_sizes, int n_in,
                              void* d_out, int out_size, void* d_ws, size_t ws_size,
                              hipStream_t stream) {
    const float* x  = (const float*)d_in[0];
    const float* W1 = (const float*)d_in[1];
    const float* W2 = (const float*)d_in[2];
    const float* bh = (const float*)d_in[3];
    const float* bo = (const float*)d_in[4];
    const int*  nit = (const int*)d_in[5];
    float* out = (float*)d_out;
    float* ws  = (float*)d_ws;

    k_setup<<<272, 256, 0, stream>>>(x, W1, bh, ws);

    double p1 = 1.0, p2 = 1.0;               // B^{t-1} at loop head
    for (int t = 1; t <= 30; ++t) {
        const float ubo1 = (t >= 2) ? (float)(1.0 / (1.0 - p1)) : 1.f;
        const float ubo2 = (t >= 2) ? (float)(1.0 / (1.0 - p2)) : 1.f;
        p1 *= (double)B1; p2 *= (double)B2;
        const float ubh1 = (float)(1.0 / (1.0 - p1));
        const float ubh2 = (float)(1.0 / (1.0 - p2));
        k_iter<<<NB, NT, 0, stream>>>(W2, bo, ws, nit, t, ubo1, ubo2, ubh1, ubh2);
    }
    k_fin<<<4, 512, 0, stream>>>(bo, ws, out, nit);
}